// Round 1
// baseline (3417.416 us; speedup 1.0000x reference)
//
#include <hip/hip_runtime.h>
#include <math.h>

#define H 128

__device__ __forceinline__ void atomAddF(float* p, float v) {
    __hip_atomic_fetch_add(p, v, __ATOMIC_RELAXED, __HIP_MEMORY_SCOPE_AGENT);
}

// deg[d] = number of in-edges (dst counts)
__global__ void deg_kernel(const int* __restrict__ ei, int E, int* __restrict__ deg) {
    int e = blockIdx.x * blockDim.x + threadIdx.x;
    if (e < E) atomicAdd(&deg[ei[E + e]], 1);
}

// dinv[i] = rsqrt(deg[i] + 1)   (+1 self-loop)
__global__ void dinv_kernel(const int* __restrict__ deg, float* __restrict__ dinv, int N) {
    int i = blockIdx.x * blockDim.x + threadIdx.x;
    if (i < N) dinv[i] = rsqrtf((float)(deg[i] + 1));
}

// aggx[i][c] = x[i][c] * dinv[i]^2   (layer-1 self-loop init, 3-wide)
__global__ void aggx_init_kernel(const float* __restrict__ x, const float* __restrict__ dinv,
                                 float* __restrict__ aggx, int N) {
    int i = blockIdx.x * blockDim.x + threadIdx.x;
    if (i >= N) return;
    float d2 = dinv[i] * dinv[i];
    aggx[3 * i + 0] = x[3 * i + 0] * d2;
    aggx[3 * i + 1] = x[3 * i + 1] * d2;
    aggx[3 * i + 2] = x[3 * i + 2] * d2;
}

// layer-1 edge scatter on RAW x (3 floats/edge): aggx[dst] += x[src] * norm
__global__ void edge3_kernel(const int* __restrict__ ei, int E, const float* __restrict__ dinv,
                             const float* __restrict__ x, float* __restrict__ aggx) {
    int e = blockIdx.x * blockDim.x + threadIdx.x;
    if (e >= E) return;
    int s = ei[e], d = ei[E + e];
    float norm = dinv[s] * dinv[d];
    atomAddF(&aggx[3 * d + 0], x[3 * s + 0] * norm);
    atomAddF(&aggx[3 * d + 1], x[3 * s + 1] * norm);
    atomAddF(&aggx[3 * d + 2], x[3 * s + 2] * norm);
}

// h1 = relu(aggx @ W1 + b1)   (N x 3) @ (3 x 128); 128 threads per node, 2 nodes/block
__global__ void h1_kernel(const float* __restrict__ aggx, const float* __restrict__ W1,
                          const float* __restrict__ b1, float* __restrict__ h1, int N) {
    __shared__ float sW[3 * H];
    __shared__ float sb[H];
    for (int t = threadIdx.x; t < 3 * H; t += blockDim.x) sW[t] = W1[t];
    if (threadIdx.x < H) sb[threadIdx.x] = b1[threadIdx.x];
    __syncthreads();
    int node = blockIdx.x * 2 + (threadIdx.x >> 7);
    int j = threadIdx.x & (H - 1);
    if (node >= N) return;
    float a0 = aggx[node * 3 + 0], a1 = aggx[node * 3 + 1], a2 = aggx[node * 3 + 2];
    float v = a0 * sW[j] + a1 * sW[H + j] + a2 * sW[2 * H + j] + sb[j];
    h1[(size_t)node * H + j] = fmaxf(v, 0.f);
}

// hB = h1 @ W2 ; agg2 = hB * dinv^2 (agg2 may alias h1: each row is consumed into
// LDS before its slot is overwritten, same block, syncthreads-protected).
#define TR 16
__global__ void gemm2_kernel(const float* __restrict__ h1, const float* __restrict__ W2,
                             const float* __restrict__ dinv,
                             float* __restrict__ hB, float* __restrict__ agg2, int N) {
    __shared__ float srow[TR][H];
    int t = threadIdx.x;
    int j = t & (H - 1);
    int g = t >> 7;  // 0 or 1: which half of the row tile this thread covers
    int ntiles = (N + TR - 1) / TR;
    for (int tile = blockIdx.x; tile < ntiles; tile += gridDim.x) {
        int base = tile * TR;
        for (int idx = t; idx < TR * H; idx += blockDim.x) {
            int r = idx >> 7, c = idx & (H - 1);
            int row = base + r;
            srow[r][c] = (row < N) ? h1[(size_t)row * H + c] : 0.f;
        }
        __syncthreads();
        float acc[TR / 2];
#pragma unroll
        for (int r = 0; r < TR / 2; r++) acc[r] = 0.f;
        for (int k = 0; k < H; k++) {
            float w = W2[k * H + j];  // coalesced, L1/L2-resident (64 KB)
#pragma unroll
            for (int r = 0; r < TR / 2; r++)
                acc[r] += srow[g * (TR / 2) + r][k] * w;  // LDS broadcast
        }
#pragma unroll
        for (int r = 0; r < TR / 2; r++) {
            int row = base + g * (TR / 2) + r;
            if (row < N) {
                float di = dinv[row];
                hB[(size_t)row * H + j] = acc[r];
                agg2[(size_t)row * H + j] = acc[r] * di * di;
            }
        }
        __syncthreads();
    }
}

// layer-2 edge scatter (128 floats/edge): 32 lanes/edge, float4 per lane
__global__ void edge_kernel(const int* __restrict__ ei, int E, const float* __restrict__ dinv,
                            const float* __restrict__ h, float* __restrict__ agg) {
    unsigned gt = blockIdx.x * blockDim.x + threadIdx.x;
    unsigned e = gt >> 5;
    unsigned lane = gt & 31u;
    if (e >= (unsigned)E) return;
    int s = ei[e], d = ei[E + e];
    float norm = dinv[s] * dinv[d];
    float4 v = ((const float4*)(h + (size_t)s * H))[lane];
    float* ap = agg + (size_t)d * H + lane * 4;
    atomAddF(ap + 0, v.x * norm);
    atomAddF(ap + 1, v.y * norm);
    atomAddF(ap + 2, v.z * norm);
    atomAddF(ap + 3, v.w * norm);
}

// per-node: v = relu(agg2 + b2); dot = v . Wc; segment-sum into graph accumulators
__global__ void pool_kernel(const float* __restrict__ agg2, const float* __restrict__ b2,
                            const float* __restrict__ Wc, const int* __restrict__ batch,
                            float* __restrict__ gsum, int* __restrict__ gcnt, int N) {
    __shared__ float sb[H];
    __shared__ float swc[H];
    if (threadIdx.x < H) {
        sb[threadIdx.x] = b2[threadIdx.x];
        swc[threadIdx.x] = Wc[threadIdx.x];
    }
    __syncthreads();
    int node = blockIdx.x * 4 + (threadIdx.x >> 6);
    int lane = threadIdx.x & 63;
    if (node >= N) return;
    float2 a = ((const float2*)(agg2 + (size_t)node * H))[lane];
    float v0 = fmaxf(a.x + sb[lane * 2 + 0], 0.f);
    float v1 = fmaxf(a.y + sb[lane * 2 + 1], 0.f);
    float dot = v0 * swc[lane * 2 + 0] + v1 * swc[lane * 2 + 1];
#pragma unroll
    for (int off = 32; off > 0; off >>= 1) dot += __shfl_down(dot, off);
    if (lane == 0) {
        int gidx = batch[node];
        atomAddF(&gsum[gidx], dot);
        atomicAdd(&gcnt[gidx], 1);
    }
}

// out[g] = sigmoid(gsum/max(cnt,1) + bc)
__global__ void out_kernel(const float* __restrict__ gsum, const int* __restrict__ gcnt,
                           const float* __restrict__ bc, float* __restrict__ out, int G) {
    int g = blockIdx.x * blockDim.x + threadIdx.x;
    if (g >= G) return;
    float c = fmaxf((float)gcnt[g], 1.f);
    float logit = gsum[g] / c + bc[0];
    out[g] = 1.f / (1.f + expf(-logit));
}

extern "C" void kernel_launch(void* const* d_in, const int* in_sizes, int n_in,
                              void* d_out, int out_size, void* d_ws, size_t ws_size,
                              hipStream_t stream) {
    const float* x     = (const float*)d_in[0];
    const int*   ei    = (const int*)d_in[1];   // [2, E] flat: row0 = src, row1 = dst
    const int*   batch = (const int*)d_in[2];
    const float* W1    = (const float*)d_in[3];
    const float* b1    = (const float*)d_in[4];
    const float* W2    = (const float*)d_in[5];
    const float* b2    = (const float*)d_in[6];
    const float* Wc    = (const float*)d_in[7];
    const float* bc    = (const float*)d_in[8];
    float* out = (float*)d_out;

    int N = in_sizes[2];
    int E = in_sizes[1] / 2;
    int G = out_size;

    char* ws = (char*)d_ws;
    size_t off = 0;
    float* buf_h   = (float*)(ws + off); off += (size_t)N * H * sizeof(float);   // hB (layer2 pre-agg)
    float* buf_agg = (float*)(ws + off); off += (size_t)N * H * sizeof(float);   // h1 / agg2
    float* aggx    = (float*)(ws + off); off += (size_t)N * 3 * sizeof(float);
    int*   deg     = (int*)  (ws + off); off += (size_t)N * sizeof(int);
    float* dinv    = (float*)(ws + off); off += (size_t)N * sizeof(float);
    float* gsum    = (float*)(ws + off); off += (size_t)G * sizeof(float);
    int*   gcnt    = (int*)  (ws + off); off += (size_t)G * sizeof(int);

    hipMemsetAsync(deg, 0, (size_t)N * sizeof(int), stream);
    hipMemsetAsync(gsum, 0, (size_t)G * sizeof(float), stream);
    hipMemsetAsync(gcnt, 0, (size_t)G * sizeof(int), stream);

    // degree + norm factors (shared by both layers)
    deg_kernel<<<(E + 255) / 256, 256, 0, stream>>>(ei, E, deg);
    dinv_kernel<<<(N + 255) / 256, 256, 0, stream>>>(deg, dinv, N);

    // ---- layer 1: aggregate raw x (3-wide), then transform ----
    aggx_init_kernel<<<(N + 255) / 256, 256, 0, stream>>>(x, dinv, aggx, N);
    edge3_kernel<<<(E + 255) / 256, 256, 0, stream>>>(ei, E, dinv, x, aggx);
    h1_kernel<<<(N + 1) / 2, 256, 0, stream>>>(aggx, W1, b1, buf_agg, N);

    // ---- layer 2: transform (GEMM) then aggregate (128-wide) ----
    gemm2_kernel<<<1024, 256, 0, stream>>>(buf_agg, W2, dinv, buf_h, buf_agg, N);
    {
        unsigned total = (unsigned)E * 32u;
        edge_kernel<<<(total + 255u) / 256u, 256, 0, stream>>>(ei, E, dinv, buf_h, buf_agg);
    }

    // ---- pool (relu+bias+dot fused) + head ----
    pool_kernel<<<(N + 3) / 4, 256, 0, stream>>>(buf_agg, b2, Wc, batch, gsum, gcnt, N);
    out_kernel<<<(G + 255) / 256, 256, 0, stream>>>(gsum, gcnt, bc, out, G);
}

// Round 2
// 626.126 us; speedup vs baseline: 5.4580x; 5.4580x over previous
//
#include <hip/hip_runtime.h>
#include <math.h>

#define H 128
#define NTPB 256
#define CHUNK 1024  // elements per scan block (256 threads x 4)
#define TR 16       // gemm row tile

__device__ __forceinline__ void atomAddF(float* p, float v) {
    __hip_atomic_fetch_add(p, v, __ATOMIC_RELAXED, __HIP_MEMORY_SCOPE_AGENT);
}

// deg[d] = number of in-edges (dst counts)
__global__ void deg_kernel(const int* __restrict__ ei, int E, int* __restrict__ deg) {
    int e = blockIdx.x * blockDim.x + threadIdx.x;
    if (e < E) atomicAdd(&deg[ei[E + e]], 1);
}

// dinv[i] = rsqrt(deg[i] + 1)   (+1 self-loop)
__global__ void dinv_kernel(const int* __restrict__ deg, float* __restrict__ dinv, int N) {
    int i = blockIdx.x * blockDim.x + threadIdx.x;
    if (i < N) dinv[i] = rsqrtf((float)(deg[i] + 1));
}

// ---- exclusive scan of deg -> rowptr (3 kernels) ----
__global__ void scan_partial(const int* __restrict__ deg, int N, int* __restrict__ partial) {
    __shared__ int sd[NTPB];
    int b = blockIdx.x, t = threadIdx.x;
    int base = b * CHUNK + t * 4;
    int s = 0;
#pragma unroll
    for (int k = 0; k < 4; k++) { int i = base + k; if (i < N) s += deg[i]; }
    sd[t] = s; __syncthreads();
    for (int off = NTPB / 2; off > 0; off >>= 1) {
        if (t < off) sd[t] += sd[t + off];
        __syncthreads();
    }
    if (t == 0) partial[b] = sd[0];
}

// serial scan of the (<=128) block sums; also writes rowptr[N] = E
__global__ void scan_tops(const int* __restrict__ partial, int nb,
                          int* __restrict__ pscan, int* __restrict__ rowptr, int N) {
    if (threadIdx.x == 0 && blockIdx.x == 0) {
        int run = 0;
        for (int b = 0; b < nb; b++) { pscan[b] = run; run += partial[b]; }
        rowptr[N] = run;
    }
}

__global__ void scan_apply(const int* __restrict__ deg, int N, const int* __restrict__ pscan,
                           int* __restrict__ rowptr, int* __restrict__ cursor) {
    __shared__ int sd[NTPB];
    int b = blockIdx.x, t = threadIdx.x;
    int base = b * CHUNK + t * 4;
    int d0 = 0, d1 = 0, d2 = 0, d3 = 0;
    if (base + 0 < N) d0 = deg[base + 0];
    if (base + 1 < N) d1 = deg[base + 1];
    if (base + 2 < N) d2 = deg[base + 2];
    if (base + 3 < N) d3 = deg[base + 3];
    int tsum = d0 + d1 + d2 + d3;
    sd[t] = tsum; __syncthreads();
    for (int s = 1; s < NTPB; s <<= 1) {
        int v = (t >= s) ? sd[t - s] : 0;
        __syncthreads();
        sd[t] += v;
        __syncthreads();
    }
    int p0 = sd[t] - tsum + pscan[b];
    int p1 = p0 + d0, p2 = p1 + d1, p3 = p2 + d2;
    if (base + 0 < N) { rowptr[base + 0] = p0; cursor[base + 0] = p0; }
    if (base + 1 < N) { rowptr[base + 1] = p1; cursor[base + 1] = p1; }
    if (base + 2 < N) { rowptr[base + 2] = p2; cursor[base + 2] = p2; }
    if (base + 3 < N) { rowptr[base + 3] = p3; cursor[base + 3] = p3; }
}

// bucket-scatter edges into dst-grouped CSR; one 8B write per edge
__global__ void scatter_kernel(const int* __restrict__ ei, int E, const float* __restrict__ dinv,
                               int* __restrict__ cursor, int2* __restrict__ csr) {
    int e = blockIdx.x * blockDim.x + threadIdx.x;
    if (e >= E) return;
    int s = ei[e], d = ei[E + e];
    int pos = atomicAdd(&cursor[d], 1);
    float w = dinv[s] * dinv[d];
    csr[pos] = make_int2(s, __float_as_int(w));
}

// layer-1 CSR gather on raw x (3-wide): aggx[n] = sum_{s in N(n)} x[s]*norm + x[n]*dinv^2
__global__ void l1_gather(const float* __restrict__ x, const float* __restrict__ dinv,
                          const int* __restrict__ rowptr, const int2* __restrict__ csr,
                          float* __restrict__ aggx, int N) {
    int n = blockIdx.x * blockDim.x + threadIdx.x;
    if (n >= N) return;
    float di = dinv[n], d2 = di * di;
    float a0 = x[3 * n + 0] * d2, a1 = x[3 * n + 1] * d2, a2 = x[3 * n + 2] * d2;
    int beg = rowptr[n], end = rowptr[n + 1];
    for (int i = beg; i < end; ++i) {
        int2 c = csr[i];
        int s = c.x; float w = __int_as_float(c.y);
        a0 += x[3 * s + 0] * w;
        a1 += x[3 * s + 1] * w;
        a2 += x[3 * s + 2] * w;
    }
    aggx[3 * n + 0] = a0; aggx[3 * n + 1] = a1; aggx[3 * n + 2] = a2;
}

// fused: h1 = relu(aggx@W1+b1) computed per-tile in LDS, then hB = h1@W2
__global__ void gemm2_fused(const float* __restrict__ aggx, const float* __restrict__ W1,
                            const float* __restrict__ b1, const float* __restrict__ W2,
                            float* __restrict__ hB, int N) {
    __shared__ float sW1[3 * H];
    __shared__ float sb1[H];
    __shared__ float sax[TR * 3];
    __shared__ float srow[TR][H];
    int t = threadIdx.x;
    for (int i = t; i < 3 * H; i += NTPB) sW1[i] = W1[i];
    if (t < H) sb1[t] = b1[t];
    int j = t & (H - 1);
    int g = t >> 7;  // which half of the row tile
    int ntiles = (N + TR - 1) / TR;
    for (int tile = blockIdx.x; tile < ntiles; tile += gridDim.x) {
        int base = tile * TR;
        __syncthreads();  // protects sax/srow reuse (and first-iter sW1/sb1 fill)
        if (t < TR * 3) {
            int idx = base * 3 + t;
            sax[t] = (idx < N * 3) ? aggx[idx] : 0.f;
        }
        __syncthreads();
        for (int idx = t; idx < TR * H; idx += NTPB) {
            int r = idx >> 7, c = idx & (H - 1);
            float v = sax[r * 3 + 0] * sW1[c] + sax[r * 3 + 1] * sW1[H + c]
                    + sax[r * 3 + 2] * sW1[2 * H + c] + sb1[c];
            srow[r][c] = fmaxf(v, 0.f);
        }
        __syncthreads();
        float acc[TR / 2];
#pragma unroll
        for (int r = 0; r < TR / 2; r++) acc[r] = 0.f;
        for (int k = 0; k < H; k++) {
            float w = W2[k * H + j];  // L1-resident after first tile
#pragma unroll
            for (int r = 0; r < TR / 2; r++)
                acc[r] += srow[g * (TR / 2) + r][k] * w;
        }
#pragma unroll
        for (int r = 0; r < TR / 2; r++) {
            int row = base + g * (TR / 2) + r;
            if (row < N) hB[(size_t)row * H + j] = acc[r];
        }
    }
}

// layer-2 CSR gather fused with bias/relu/Wc-dot/segment-sum.
// One 64-lane wave per dst node; lane holds float2 of the row.
__global__ void gather_pool(const float* __restrict__ hB, const float* __restrict__ dinv,
                            const int* __restrict__ rowptr, const int2* __restrict__ csr,
                            const float* __restrict__ b2, const float* __restrict__ Wc,
                            const int* __restrict__ batch,
                            float* __restrict__ gsum, int* __restrict__ gcnt, int N) {
    __shared__ float sb2[H];
    __shared__ float swc[H];
    int t = threadIdx.x;
    if (t < H) { sb2[t] = b2[t]; swc[t] = Wc[t]; }
    __syncthreads();
    int node = blockIdx.x * (NTPB / 64) + (t >> 6);
    int lane = t & 63;
    if (node >= N) return;
    const float2* __restrict__ hb2 = (const float2*)hB;
    float di = dinv[node], d2 = di * di;
    float2 hs = hb2[(size_t)node * 64 + lane];
    float ax = hs.x * d2, ay = hs.y * d2;
    int beg = rowptr[node], end = rowptr[node + 1];
    int i = beg;
    for (; i + 1 < end; i += 2) {  // 2-edge unroll: both row loads in flight
        int2 cA = csr[i], cB = csr[i + 1];
        float2 vA = hb2[(size_t)cA.x * 64 + lane];
        float2 vB = hb2[(size_t)cB.x * 64 + lane];
        float wA = __int_as_float(cA.y), wB = __int_as_float(cB.y);
        ax += vA.x * wA + vB.x * wB;
        ay += vA.y * wA + vB.y * wB;
    }
    if (i < end) {
        int2 c = csr[i];
        float2 v = hb2[(size_t)c.x * 64 + lane];
        float w = __int_as_float(c.y);
        ax += v.x * w; ay += v.y * w;
    }
    float v0 = fmaxf(ax + sb2[2 * lane + 0], 0.f);
    float v1 = fmaxf(ay + sb2[2 * lane + 1], 0.f);
    float dot = v0 * swc[2 * lane + 0] + v1 * swc[2 * lane + 1];
#pragma unroll
    for (int off = 32; off > 0; off >>= 1) dot += __shfl_down(dot, off);
    if (lane == 0) {
        int gidx = batch[node];
        atomAddF(&gsum[gidx], dot);
        atomicAdd(&gcnt[gidx], 1);
    }
}

__global__ void out_kernel(const float* __restrict__ gsum, const int* __restrict__ gcnt,
                           const float* __restrict__ bc, float* __restrict__ out, int G) {
    int g = blockIdx.x * blockDim.x + threadIdx.x;
    if (g >= G) return;
    float c = fmaxf((float)gcnt[g], 1.f);
    float logit = gsum[g] / c + bc[0];
    out[g] = 1.f / (1.f + expf(-logit));
}

extern "C" void kernel_launch(void* const* d_in, const int* in_sizes, int n_in,
                              void* d_out, int out_size, void* d_ws, size_t ws_size,
                              hipStream_t stream) {
    const float* x     = (const float*)d_in[0];
    const int*   ei    = (const int*)d_in[1];
    const int*   batch = (const int*)d_in[2];
    const float* W1    = (const float*)d_in[3];
    const float* b1    = (const float*)d_in[4];
    const float* W2    = (const float*)d_in[5];
    const float* b2    = (const float*)d_in[6];
    const float* Wc    = (const float*)d_in[7];
    const float* bc    = (const float*)d_in[8];
    float* out = (float*)d_out;

    int N = in_sizes[2];
    int E = in_sizes[1] / 2;
    int G = out_size;
    int NB = (N + CHUNK - 1) / CHUNK;

    char* ws = (char*)d_ws;
    size_t off = 0;
    auto alloc = [&](size_t bytes) {
        void* p = ws + off;
        off += (bytes + 255) & ~(size_t)255;
        return p;
    };
    float* hB     = (float*)alloc((size_t)N * H * sizeof(float));
    float* aggx   = (float*)alloc((size_t)N * 3 * sizeof(float));
    int*   deg    = (int*)  alloc((size_t)N * sizeof(int));
    int*   rowptr = (int*)  alloc((size_t)(N + 1) * sizeof(int));
    int*   cursor = (int*)  alloc((size_t)N * sizeof(int));
    float* dinv   = (float*)alloc((size_t)N * sizeof(float));
    int2*  csr    = (int2*) alloc((size_t)E * sizeof(int2));
    int*   partial= (int*)  alloc((size_t)NB * sizeof(int));
    int*   pscan  = (int*)  alloc((size_t)NB * sizeof(int));
    float* gsum   = (float*)alloc((size_t)G * sizeof(float));
    int*   gcnt   = (int*)  alloc((size_t)G * sizeof(int));

    hipMemsetAsync(deg, 0, (size_t)N * sizeof(int), stream);
    hipMemsetAsync(gsum, 0, (size_t)G * sizeof(float), stream);
    hipMemsetAsync(gcnt, 0, (size_t)G * sizeof(int), stream);

    deg_kernel<<<(E + NTPB - 1) / NTPB, NTPB, 0, stream>>>(ei, E, deg);
    dinv_kernel<<<(N + NTPB - 1) / NTPB, NTPB, 0, stream>>>(deg, dinv, N);

    scan_partial<<<NB, NTPB, 0, stream>>>(deg, N, partial);
    scan_tops<<<1, 64, 0, stream>>>(partial, NB, pscan, rowptr, N);
    scan_apply<<<NB, NTPB, 0, stream>>>(deg, N, pscan, rowptr, cursor);

    scatter_kernel<<<(E + NTPB - 1) / NTPB, NTPB, 0, stream>>>(ei, E, dinv, cursor, csr);

    l1_gather<<<(N + NTPB - 1) / NTPB, NTPB, 0, stream>>>(x, dinv, rowptr, csr, aggx, N);

    gemm2_fused<<<2048, NTPB, 0, stream>>>(aggx, W1, b1, W2, hB, N);

    gather_pool<<<(N + 3) / 4, NTPB, 0, stream>>>(hB, dinv, rowptr, csr, b2, Wc, batch,
                                                  gsum, gcnt, N);

    out_kernel<<<(G + NTPB - 1) / NTPB, NTPB, 0, stream>>>(gsum, gcnt, bc, out, G);
}

// Round 3
// 624.015 us; speedup vs baseline: 5.4765x; 1.0034x over previous
//
#include <hip/hip_runtime.h>
#include <hip/hip_bf16.h>
#include <math.h>

#define H 128
#define NTPB 256
#define CHUNK 1024  // elements per scan block (256 threads x 4)
#define TR 32       // gemm row tile

__device__ __forceinline__ void atomAddF(float* p, float v) {
    __hip_atomic_fetch_add(p, v, __ATOMIC_RELAXED, __HIP_MEMORY_SCOPE_AGENT);
}

// deg[d] = number of in-edges (dst counts)
__global__ void deg_kernel(const int* __restrict__ ei, int E, int* __restrict__ deg) {
    int e = blockIdx.x * blockDim.x + threadIdx.x;
    if (e < E) atomicAdd(&deg[ei[E + e]], 1);
}

// ---- exclusive scan of deg -> rowptr ----
__global__ void scan_partial(const int* __restrict__ deg, int N, int* __restrict__ partial) {
    __shared__ int sd[NTPB];
    int b = blockIdx.x, t = threadIdx.x;
    int base = b * CHUNK + t * 4;
    int s = 0;
#pragma unroll
    for (int k = 0; k < 4; k++) { int i = base + k; if (i < N) s += deg[i]; }
    sd[t] = s; __syncthreads();
    for (int off = NTPB / 2; off > 0; off >>= 1) {
        if (t < off) sd[t] += sd[t + off];
        __syncthreads();
    }
    if (t == 0) partial[b] = sd[0];
}

__global__ void scan_tops(const int* __restrict__ partial, int nb,
                          int* __restrict__ pscan, int* __restrict__ rowptr, int N) {
    if (threadIdx.x == 0 && blockIdx.x == 0) {
        int run = 0;
        for (int b = 0; b < nb; b++) { pscan[b] = run; run += partial[b]; }
        rowptr[N] = run;
    }
}

// also emits dinv (folded to save a pass)
__global__ void scan_apply(const int* __restrict__ deg, int N, const int* __restrict__ pscan,
                           int* __restrict__ rowptr, int* __restrict__ cursor,
                           float* __restrict__ dinv) {
    __shared__ int sd[NTPB];
    int b = blockIdx.x, t = threadIdx.x;
    int base = b * CHUNK + t * 4;
    int d0 = 0, d1 = 0, d2 = 0, d3 = 0;
    if (base + 0 < N) d0 = deg[base + 0];
    if (base + 1 < N) d1 = deg[base + 1];
    if (base + 2 < N) d2 = deg[base + 2];
    if (base + 3 < N) d3 = deg[base + 3];
    int tsum = d0 + d1 + d2 + d3;
    sd[t] = tsum; __syncthreads();
    for (int s = 1; s < NTPB; s <<= 1) {
        int v = (t >= s) ? sd[t - s] : 0;
        __syncthreads();
        sd[t] += v;
        __syncthreads();
    }
    int p0 = sd[t] - tsum + pscan[b];
    int p1 = p0 + d0, p2 = p1 + d1, p3 = p2 + d2;
    if (base + 0 < N) { rowptr[base + 0] = p0; cursor[base + 0] = p0; dinv[base + 0] = rsqrtf((float)(d0 + 1)); }
    if (base + 1 < N) { rowptr[base + 1] = p1; cursor[base + 1] = p1; dinv[base + 1] = rsqrtf((float)(d1 + 1)); }
    if (base + 2 < N) { rowptr[base + 2] = p2; cursor[base + 2] = p2; dinv[base + 2] = rsqrtf((float)(d2 + 1)); }
    if (base + 3 < N) { rowptr[base + 3] = p3; cursor[base + 3] = p3; dinv[base + 3] = rsqrtf((float)(d3 + 1)); }
}

// bucket-scatter: dst-grouped src list, 4 B per edge
__global__ void scatter_kernel(const int* __restrict__ ei, int E,
                               int* __restrict__ cursor, int* __restrict__ csrc) {
    int e = blockIdx.x * blockDim.x + threadIdx.x;
    if (e >= E) return;
    int s = ei[e], d = ei[E + e];
    int pos = atomicAdd(&cursor[d], 1);
    csrc[pos] = s;
}

// layer-1 CSR gather on raw x (3-wide)
__global__ void l1_gather(const float* __restrict__ x, const float* __restrict__ dinv,
                          const int* __restrict__ rowptr, const int* __restrict__ csrc,
                          float* __restrict__ aggx, int N) {
    int n = blockIdx.x * blockDim.x + threadIdx.x;
    if (n >= N) return;
    float di = dinv[n], d2 = di * di;
    float a0 = x[3 * n + 0] * d2, a1 = x[3 * n + 1] * d2, a2 = x[3 * n + 2] * d2;
    int beg = rowptr[n], end = rowptr[n + 1];
    for (int i = beg; i < end; ++i) {
        int s = csrc[i];
        float w = dinv[s] * di;
        a0 += x[3 * s + 0] * w;
        a1 += x[3 * s + 1] * w;
        a2 += x[3 * s + 2] * w;
    }
    aggx[3 * n + 0] = a0; aggx[3 * n + 1] = a1; aggx[3 * n + 2] = a2;
}

// fused: h1 = relu(aggx@W1+b1) per-tile in LDS, then hB = bf16(h1@W2)
__global__ void gemm2_fused(const float* __restrict__ aggx, const float* __restrict__ W1,
                            const float* __restrict__ b1, const float* __restrict__ W2,
                            __hip_bfloat16* __restrict__ hBb, int N) {
    __shared__ float sW1[3 * H];
    __shared__ float sb1[H];
    __shared__ float sax[TR * 3];
    __shared__ float srow[TR][H];
    int t = threadIdx.x;
    for (int i = t; i < 3 * H; i += NTPB) sW1[i] = W1[i];
    if (t < H) sb1[t] = b1[t];
    int j = t & (H - 1);
    int g = t >> 7;  // which half of the row tile (16 rows each)
    int ntiles = (N + TR - 1) / TR;
    for (int tile = blockIdx.x; tile < ntiles; tile += gridDim.x) {
        int base = tile * TR;
        __syncthreads();
        if (t < TR * 3) {
            int idx = base * 3 + t;
            sax[t] = (idx < N * 3) ? aggx[idx] : 0.f;
        }
        __syncthreads();
        for (int idx = t; idx < TR * H; idx += NTPB) {
            int r = idx >> 7, c = idx & (H - 1);
            float v = sax[r * 3 + 0] * sW1[c] + sax[r * 3 + 1] * sW1[H + c]
                    + sax[r * 3 + 2] * sW1[2 * H + c] + sb1[c];
            srow[r][c] = fmaxf(v, 0.f);
        }
        __syncthreads();
        float acc[TR / 2];
#pragma unroll
        for (int r = 0; r < TR / 2; r++) acc[r] = 0.f;
        for (int k = 0; k < H; k += 2) {
            float w0 = W2[k * H + j];         // L1-resident after first tile
            float w1 = W2[(k + 1) * H + j];
#pragma unroll
            for (int r = 0; r < TR / 2; r++) {
                float2 s = *(const float2*)&srow[g * (TR / 2) + r][k];
                acc[r] += s.x * w0 + s.y * w1;
            }
        }
#pragma unroll
        for (int r = 0; r < TR / 2; r++) {
            int row = base + g * (TR / 2) + r;
            if (row < N) hBb[(size_t)row * H + j] = __float2bfloat16(acc[r]);
        }
    }
}

// layer-2 CSR gather (bf16 rows, 256 B) fused with bias/relu/Wc-dot/segment-sum.
// One 64-lane wave per dst node; lane holds a packed bf16 pair (dims 2*lane, 2*lane+1).
__global__ void gather_pool(const unsigned* __restrict__ hBu, const float* __restrict__ dinv,
                            const int* __restrict__ rowptr, const int* __restrict__ csrc,
                            const float* __restrict__ b2, const float* __restrict__ Wc,
                            const int* __restrict__ batch,
                            float* __restrict__ gsum, int* __restrict__ gcnt, int N) {
    __shared__ float sb2[H];
    __shared__ float swc[H];
    int t = threadIdx.x;
    if (t < H) { sb2[t] = b2[t]; swc[t] = Wc[t]; }
    __syncthreads();
    int node = blockIdx.x * (NTPB / 64) + (t >> 6);
    int lane = t & 63;
    if (node >= N) return;
    float di = dinv[node], d2 = di * di;
    unsigned ps = hBu[(size_t)node * 64 + lane];
    float ax = __uint_as_float(ps << 16) * d2;
    float ay = __uint_as_float(ps & 0xffff0000u) * d2;
    int beg = rowptr[node], end = rowptr[node + 1];
    int i = beg;
    for (; i + 4 <= end; i += 4) {   // 4 independent 256 B row loads in flight
        int s0 = csrc[i], s1 = csrc[i + 1], s2 = csrc[i + 2], s3 = csrc[i + 3];
        float w0 = dinv[s0] * di, w1 = dinv[s1] * di, w2 = dinv[s2] * di, w3 = dinv[s3] * di;
        unsigned p0 = hBu[(size_t)s0 * 64 + lane];
        unsigned p1 = hBu[(size_t)s1 * 64 + lane];
        unsigned p2 = hBu[(size_t)s2 * 64 + lane];
        unsigned p3 = hBu[(size_t)s3 * 64 + lane];
        ax += __uint_as_float(p0 << 16) * w0 + __uint_as_float(p1 << 16) * w1
            + __uint_as_float(p2 << 16) * w2 + __uint_as_float(p3 << 16) * w3;
        ay += __uint_as_float(p0 & 0xffff0000u) * w0 + __uint_as_float(p1 & 0xffff0000u) * w1
            + __uint_as_float(p2 & 0xffff0000u) * w2 + __uint_as_float(p3 & 0xffff0000u) * w3;
    }
    for (; i < end; ++i) {
        int s = csrc[i];
        float w = dinv[s] * di;
        unsigned p = hBu[(size_t)s * 64 + lane];
        ax += __uint_as_float(p << 16) * w;
        ay += __uint_as_float(p & 0xffff0000u) * w;
    }
    float v0 = fmaxf(ax + sb2[2 * lane + 0], 0.f);
    float v1 = fmaxf(ay + sb2[2 * lane + 1], 0.f);
    float dot = v0 * swc[2 * lane + 0] + v1 * swc[2 * lane + 1];
#pragma unroll
    for (int off = 32; off > 0; off >>= 1) dot += __shfl_down(dot, off);
    if (lane == 0) {
        int gidx = batch[node];
        atomAddF(&gsum[gidx], dot);
        atomicAdd(&gcnt[gidx], 1);
    }
}

__global__ void out_kernel(const float* __restrict__ gsum, const int* __restrict__ gcnt,
                           const float* __restrict__ bc, float* __restrict__ out, int G) {
    int g = blockIdx.x * blockDim.x + threadIdx.x;
    if (g >= G) return;
    float c = fmaxf((float)gcnt[g], 1.f);
    float logit = gsum[g] / c + bc[0];
    out[g] = 1.f / (1.f + expf(-logit));
}

extern "C" void kernel_launch(void* const* d_in, const int* in_sizes, int n_in,
                              void* d_out, int out_size, void* d_ws, size_t ws_size,
                              hipStream_t stream) {
    const float* x     = (const float*)d_in[0];
    const int*   ei    = (const int*)d_in[1];
    const int*   batch = (const int*)d_in[2];
    const float* W1    = (const float*)d_in[3];
    const float* b1    = (const float*)d_in[4];
    const float* W2    = (const float*)d_in[5];
    const float* b2    = (const float*)d_in[6];
    const float* Wc    = (const float*)d_in[7];
    const float* bc    = (const float*)d_in[8];
    float* out = (float*)d_out;

    int N = in_sizes[2];
    int E = in_sizes[1] / 2;
    int G = out_size;
    int NB = (N + CHUNK - 1) / CHUNK;

    char* ws = (char*)d_ws;
    size_t off = 0;
    auto alloc = [&](size_t bytes) {
        void* p = ws + off;
        off += (bytes + 255) & ~(size_t)255;
        return p;
    };
    __hip_bfloat16* hBb = (__hip_bfloat16*)alloc((size_t)N * H * sizeof(__hip_bfloat16));
    float* aggx   = (float*)alloc((size_t)N * 3 * sizeof(float));
    int*   deg    = (int*)  alloc((size_t)N * sizeof(int));
    int*   rowptr = (int*)  alloc((size_t)(N + 1) * sizeof(int));
    int*   cursor = (int*)  alloc((size_t)N * sizeof(int));
    float* dinv   = (float*)alloc((size_t)N * sizeof(float));
    int*   csrc   = (int*)  alloc((size_t)E * sizeof(int));
    int*   partial= (int*)  alloc((size_t)NB * sizeof(int));
    int*   pscan  = (int*)  alloc((size_t)NB * sizeof(int));
    float* gsum   = (float*)alloc((size_t)G * sizeof(float));
    int*   gcnt   = (int*)  alloc((size_t)G * sizeof(int));

    hipMemsetAsync(deg, 0, (size_t)N * sizeof(int), stream);
    hipMemsetAsync(gsum, 0, (size_t)G * sizeof(float), stream);
    hipMemsetAsync(gcnt, 0, (size_t)G * sizeof(int), stream);

    deg_kernel<<<(E + NTPB - 1) / NTPB, NTPB, 0, stream>>>(ei, E, deg);

    scan_partial<<<NB, NTPB, 0, stream>>>(deg, N, partial);
    scan_tops<<<1, 64, 0, stream>>>(partial, NB, pscan, rowptr, N);
    scan_apply<<<NB, NTPB, 0, stream>>>(deg, N, pscan, rowptr, cursor, dinv);

    scatter_kernel<<<(E + NTPB - 1) / NTPB, NTPB, 0, stream>>>(ei, E, cursor, csrc);

    l1_gather<<<(N + NTPB - 1) / NTPB, NTPB, 0, stream>>>(x, dinv, rowptr, csrc, aggx, N);

    {
        int ntiles = (N + TR - 1) / TR;
        gemm2_fused<<<ntiles, NTPB, 0, stream>>>(aggx, W1, b1, W2, hBb, N);
    }

    gather_pool<<<(N + 3) / 4, NTPB, 0, stream>>>((const unsigned*)hBb, dinv, rowptr, csrc,
                                                  b2, Wc, batch, gsum, gcnt, N);

    out_kernel<<<(G + NTPB - 1) / NTPB, NTPB, 0, stream>>>(gsum, gcnt, bc, out, G);
}

// Round 4
// 575.976 us; speedup vs baseline: 5.9333x; 1.0834x over previous
//
#include <hip/hip_runtime.h>
#include <hip/hip_bf16.h>
#include <math.h>

#define H 128
#define NTPB 256
#define CHUNK 1024  // elements per scan block (256 threads x 4)
#define TR 32       // gemm row tile
#define GP_WPB 4    // gather_pool waves per block

__device__ __forceinline__ void atomAddF(float* p, float v) {
    __hip_atomic_fetch_add(p, v, __ATOMIC_RELAXED, __HIP_MEMORY_SCOPE_AGENT);
}

// deg[d] = number of in-edges (dst counts)
__global__ void deg_kernel(const int* __restrict__ ei, int E, int* __restrict__ deg) {
    int e = blockIdx.x * blockDim.x + threadIdx.x;
    if (e < E) atomicAdd(&deg[ei[E + e]], 1);
}

// ---- exclusive scan of deg -> rowptr ----
__global__ void scan_partial(const int* __restrict__ deg, int N, int* __restrict__ partial) {
    __shared__ int sd[NTPB];
    int b = blockIdx.x, t = threadIdx.x;
    int base = b * CHUNK + t * 4;
    int s = 0;
#pragma unroll
    for (int k = 0; k < 4; k++) { int i = base + k; if (i < N) s += deg[i]; }
    sd[t] = s; __syncthreads();
    for (int off = NTPB / 2; off > 0; off >>= 1) {
        if (t < off) sd[t] += sd[t + off];
        __syncthreads();
    }
    if (t == 0) partial[b] = sd[0];
}

__global__ void scan_tops(const int* __restrict__ partial, int nb,
                          int* __restrict__ pscan, int* __restrict__ rowptr, int N) {
    if (threadIdx.x == 0 && blockIdx.x == 0) {
        int run = 0;
        for (int b = 0; b < nb; b++) { pscan[b] = run; run += partial[b]; }
        rowptr[N] = run;
    }
}

// also emits dinv
__global__ void scan_apply(const int* __restrict__ deg, int N, const int* __restrict__ pscan,
                           int* __restrict__ rowptr, int* __restrict__ cursor,
                           float* __restrict__ dinv) {
    __shared__ int sd[NTPB];
    int b = blockIdx.x, t = threadIdx.x;
    int base = b * CHUNK + t * 4;
    int d0 = 0, d1 = 0, d2 = 0, d3 = 0;
    if (base + 0 < N) d0 = deg[base + 0];
    if (base + 1 < N) d1 = deg[base + 1];
    if (base + 2 < N) d2 = deg[base + 2];
    if (base + 3 < N) d3 = deg[base + 3];
    int tsum = d0 + d1 + d2 + d3;
    sd[t] = tsum; __syncthreads();
    for (int s = 1; s < NTPB; s <<= 1) {
        int v = (t >= s) ? sd[t - s] : 0;
        __syncthreads();
        sd[t] += v;
        __syncthreads();
    }
    int p0 = sd[t] - tsum + pscan[b];
    int p1 = p0 + d0, p2 = p1 + d1, p3 = p2 + d2;
    if (base + 0 < N) { rowptr[base + 0] = p0; cursor[base + 0] = p0; dinv[base + 0] = rsqrtf((float)(d0 + 1)); }
    if (base + 1 < N) { rowptr[base + 1] = p1; cursor[base + 1] = p1; dinv[base + 1] = rsqrtf((float)(d1 + 1)); }
    if (base + 2 < N) { rowptr[base + 2] = p2; cursor[base + 2] = p2; dinv[base + 2] = rsqrtf((float)(d2 + 1)); }
    if (base + 3 < N) { rowptr[base + 3] = p3; cursor[base + 3] = p3; dinv[base + 3] = rsqrtf((float)(d3 + 1)); }
}

// bucket-scatter: dst-grouped {src, w} (8 B/edge); w precomputed to kill chains in gathers
__global__ void scatter_kernel(const int* __restrict__ ei, int E, const float* __restrict__ dinv,
                               int* __restrict__ cursor, int2* __restrict__ csr) {
    int e = blockIdx.x * blockDim.x + threadIdx.x;
    if (e >= E) return;
    int s = ei[e], d = ei[E + e];
    int pos = atomicAdd(&cursor[d], 1);
    float w = dinv[s] * dinv[d];
    csr[pos] = make_int2(s, __float_as_int(w));
}

// layer-1 CSR gather on raw x (3-wide), 2-edge unroll
__global__ void l1_gather(const float* __restrict__ x, const float* __restrict__ dinv,
                          const int* __restrict__ rowptr, const int2* __restrict__ csr,
                          float* __restrict__ aggx, int N) {
    int n = blockIdx.x * blockDim.x + threadIdx.x;
    if (n >= N) return;
    float di = dinv[n], d2 = di * di;
    float a0 = x[3 * n + 0] * d2, a1 = x[3 * n + 1] * d2, a2 = x[3 * n + 2] * d2;
    int beg = rowptr[n], end = rowptr[n + 1];
    int i = beg;
    for (; i + 2 <= end; i += 2) {
        int2 cA = csr[i], cB = csr[i + 1];
        float wA = __int_as_float(cA.y), wB = __int_as_float(cB.y);
        a0 += x[3 * cA.x + 0] * wA + x[3 * cB.x + 0] * wB;
        a1 += x[3 * cA.x + 1] * wA + x[3 * cB.x + 1] * wB;
        a2 += x[3 * cA.x + 2] * wA + x[3 * cB.x + 2] * wB;
    }
    if (i < end) {
        int2 c = csr[i];
        float w = __int_as_float(c.y);
        a0 += x[3 * c.x + 0] * w;
        a1 += x[3 * c.x + 1] * w;
        a2 += x[3 * c.x + 2] * w;
    }
    aggx[3 * n + 0] = a0; aggx[3 * n + 1] = a1; aggx[3 * n + 2] = a2;
}

// fused: h1 = relu(aggx@W1+b1) per-tile in LDS, then hB = bf16(h1@W2)
__global__ void gemm2_fused(const float* __restrict__ aggx, const float* __restrict__ W1,
                            const float* __restrict__ b1, const float* __restrict__ W2,
                            __hip_bfloat16* __restrict__ hBb, int N) {
    __shared__ float sW1[3 * H];
    __shared__ float sb1[H];
    __shared__ float sax[TR * 3];
    __shared__ float srow[TR][H];
    int t = threadIdx.x;
    for (int i = t; i < 3 * H; i += NTPB) sW1[i] = W1[i];
    if (t < H) sb1[t] = b1[t];
    int j = t & (H - 1);
    int g = t >> 7;
    int ntiles = (N + TR - 1) / TR;
    for (int tile = blockIdx.x; tile < ntiles; tile += gridDim.x) {
        int base = tile * TR;
        __syncthreads();
        if (t < TR * 3) {
            int idx = base * 3 + t;
            sax[t] = (idx < N * 3) ? aggx[idx] : 0.f;
        }
        __syncthreads();
        for (int idx = t; idx < TR * H; idx += NTPB) {
            int r = idx >> 7, c = idx & (H - 1);
            float v = sax[r * 3 + 0] * sW1[c] + sax[r * 3 + 1] * sW1[H + c]
                    + sax[r * 3 + 2] * sW1[2 * H + c] + sb1[c];
            srow[r][c] = fmaxf(v, 0.f);
        }
        __syncthreads();
        float acc[TR / 2];
#pragma unroll
        for (int r = 0; r < TR / 2; r++) acc[r] = 0.f;
        for (int k = 0; k < H; k += 2) {
            float w0 = W2[k * H + j];
            float w1 = W2[(k + 1) * H + j];
#pragma unroll
            for (int r = 0; r < TR / 2; r++) {
                float2 s = *(const float2*)&srow[g * (TR / 2) + r][k];
                acc[r] += s.x * w0 + s.y * w1;
            }
        }
#pragma unroll
        for (int r = 0; r < TR / 2; r++) {
            int row = base + g * (TR / 2) + r;
            if (row < N) hBb[(size_t)row * H + j] = __float2bfloat16(acc[r]);
        }
    }
}

// layer-2 gather: wave per dst node. Lane-parallel edge preload into LDS,
// then 8 independent 256B row loads in flight per round (no address chains).
__global__ void gather_pool(const unsigned* __restrict__ hBu, const float* __restrict__ dinv,
                            const int* __restrict__ rowptr, const int2* __restrict__ csr,
                            const float* __restrict__ b2, const float* __restrict__ Wc,
                            const int* __restrict__ batch,
                            float* __restrict__ gsum, int* __restrict__ gcnt, int N) {
    __shared__ float sb2[H];
    __shared__ float swc[H];
    __shared__ int2 sls[GP_WPB][64];
    int t = threadIdx.x;
    if (t < H) { sb2[t] = b2[t]; swc[t] = Wc[t]; }
    __syncthreads();
    int wv = t >> 6, lane = t & 63;
    int node = blockIdx.x * GP_WPB + wv;
    if (node >= N) return;
    float di = dinv[node], d2 = di * di;
    unsigned ps = hBu[(size_t)node * 64 + lane];
    float ax = __uint_as_float(ps << 16) * d2;
    float ay = __uint_as_float(ps & 0xffff0000u) * d2;
    int beg = rowptr[node], end = rowptr[node + 1];
    for (int base = beg; base < end; base += 64) {
        int m = end - base; if (m > 64) m = 64;
        // cooperative preload: one coalesced int2 load covers up to 64 edges
        int2 c = (lane < m) ? csr[base + lane] : make_int2(0, 0);
        sls[wv][lane] = c;  // same-wave LDS: compiler inserts lgkmcnt, no barrier needed
        int m8 = (m + 7) & ~7;  // padded slots are {src=0, w=0}: harmless L1-hot row-0 loads
        for (int k = 0; k < m8; k += 8) {
            int2 c0 = sls[wv][k + 0], c1 = sls[wv][k + 1], c2 = sls[wv][k + 2], c3 = sls[wv][k + 3];
            int2 c4 = sls[wv][k + 4], c5 = sls[wv][k + 5], c6 = sls[wv][k + 6], c7 = sls[wv][k + 7];
            unsigned p0 = hBu[(size_t)c0.x * 64 + lane];
            unsigned p1 = hBu[(size_t)c1.x * 64 + lane];
            unsigned p2 = hBu[(size_t)c2.x * 64 + lane];
            unsigned p3 = hBu[(size_t)c3.x * 64 + lane];
            unsigned p4 = hBu[(size_t)c4.x * 64 + lane];
            unsigned p5 = hBu[(size_t)c5.x * 64 + lane];
            unsigned p6 = hBu[(size_t)c6.x * 64 + lane];
            unsigned p7 = hBu[(size_t)c7.x * 64 + lane];
            float w0 = __int_as_float(c0.y), w1 = __int_as_float(c1.y);
            float w2 = __int_as_float(c2.y), w3 = __int_as_float(c3.y);
            float w4 = __int_as_float(c4.y), w5 = __int_as_float(c5.y);
            float w6 = __int_as_float(c6.y), w7 = __int_as_float(c7.y);
            ax += __uint_as_float(p0 << 16) * w0 + __uint_as_float(p1 << 16) * w1
                + __uint_as_float(p2 << 16) * w2 + __uint_as_float(p3 << 16) * w3
                + __uint_as_float(p4 << 16) * w4 + __uint_as_float(p5 << 16) * w5
                + __uint_as_float(p6 << 16) * w6 + __uint_as_float(p7 << 16) * w7;
            ay += __uint_as_float(p0 & 0xffff0000u) * w0 + __uint_as_float(p1 & 0xffff0000u) * w1
                + __uint_as_float(p2 & 0xffff0000u) * w2 + __uint_as_float(p3 & 0xffff0000u) * w3
                + __uint_as_float(p4 & 0xffff0000u) * w4 + __uint_as_float(p5 & 0xffff0000u) * w5
                + __uint_as_float(p6 & 0xffff0000u) * w6 + __uint_as_float(p7 & 0xffff0000u) * w7;
        }
    }
    float v0 = fmaxf(ax + sb2[2 * lane + 0], 0.f);
    float v1 = fmaxf(ay + sb2[2 * lane + 1], 0.f);
    float dot = v0 * swc[2 * lane + 0] + v1 * swc[2 * lane + 1];
#pragma unroll
    for (int off = 32; off > 0; off >>= 1) dot += __shfl_down(dot, off);
    if (lane == 0) {
        int gidx = batch[node];
        atomAddF(&gsum[gidx], dot);
        atomicAdd(&gcnt[gidx], 1);
    }
}

__global__ void out_kernel(const float* __restrict__ gsum, const int* __restrict__ gcnt,
                           const float* __restrict__ bc, float* __restrict__ out, int G) {
    int g = blockIdx.x * blockDim.x + threadIdx.x;
    if (g >= G) return;
    float c = fmaxf((float)gcnt[g], 1.f);
    float logit = gsum[g] / c + bc[0];
    out[g] = 1.f / (1.f + expf(-logit));
}

extern "C" void kernel_launch(void* const* d_in, const int* in_sizes, int n_in,
                              void* d_out, int out_size, void* d_ws, size_t ws_size,
                              hipStream_t stream) {
    const float* x     = (const float*)d_in[0];
    const int*   ei    = (const int*)d_in[1];
    const int*   batch = (const int*)d_in[2];
    const float* W1    = (const float*)d_in[3];
    const float* b1    = (const float*)d_in[4];
    const float* W2    = (const float*)d_in[5];
    const float* b2    = (const float*)d_in[6];
    const float* Wc    = (const float*)d_in[7];
    const float* bc    = (const float*)d_in[8];
    float* out = (float*)d_out;

    int N = in_sizes[2];
    int E = in_sizes[1] / 2;
    int G = out_size;
    int NB = (N + CHUNK - 1) / CHUNK;

    char* ws = (char*)d_ws;
    size_t off = 0;
    auto alloc = [&](size_t bytes) {
        void* p = ws + off;
        off += (bytes + 255) & ~(size_t)255;
        return p;
    };
    __hip_bfloat16* hBb = (__hip_bfloat16*)alloc((size_t)N * H * sizeof(__hip_bfloat16));
    float* aggx   = (float*)alloc((size_t)N * 3 * sizeof(float));
    // deg/gsum/gcnt contiguous -> single memset
    int*   deg    = (int*)  alloc((size_t)N * sizeof(int));
    float* gsum   = (float*)alloc((size_t)G * sizeof(float));
    int*   gcnt   = (int*)  alloc((size_t)G * sizeof(int));
    char*  zero_end = ws + off;
    int*   rowptr = (int*)  alloc((size_t)(N + 1) * sizeof(int));
    int*   cursor = (int*)  alloc((size_t)N * sizeof(int));
    float* dinv   = (float*)alloc((size_t)N * sizeof(float));
    int2*  csr    = (int2*) alloc((size_t)E * sizeof(int2));
    int*   partial= (int*)  alloc((size_t)NB * sizeof(int));
    int*   pscan  = (int*)  alloc((size_t)NB * sizeof(int));

    hipMemsetAsync(deg, 0, (size_t)(zero_end - (char*)deg), stream);

    deg_kernel<<<(E + NTPB - 1) / NTPB, NTPB, 0, stream>>>(ei, E, deg);

    scan_partial<<<NB, NTPB, 0, stream>>>(deg, N, partial);
    scan_tops<<<1, 64, 0, stream>>>(partial, NB, pscan, rowptr, N);
    scan_apply<<<NB, NTPB, 0, stream>>>(deg, N, pscan, rowptr, cursor, dinv);

    scatter_kernel<<<(E + NTPB - 1) / NTPB, NTPB, 0, stream>>>(ei, E, dinv, cursor, csr);

    l1_gather<<<(N + NTPB - 1) / NTPB, NTPB, 0, stream>>>(x, dinv, rowptr, csr, aggx, N);

    {
        int ntiles = (N + TR - 1) / TR;
        gemm2_fused<<<ntiles, NTPB, 0, stream>>>(aggx, W1, b1, W2, hBb, N);
    }

    gather_pool<<<(N + GP_WPB - 1) / GP_WPB, NTPB, 0, stream>>>(
        (const unsigned*)hBb, dinv, rowptr, csr, b2, Wc, batch, gsum, gcnt, N);

    out_kernel<<<(G + NTPB - 1) / NTPB, NTPB, 0, stream>>>(gsum, gcnt, bc, out, G);
}

// Round 6
// 531.023 us; speedup vs baseline: 6.4355x; 1.0847x over previous
//
#include <hip/hip_runtime.h>
#include <hip/hip_bf16.h>
#include <math.h>

#define H 128
#define NTPB 256
#define CHUNK 1024  // elements per scan block (256 threads x 4)
#define GP_WPB 4    // gather_pool waves per block

typedef __attribute__((ext_vector_type(8))) short short8;
typedef __attribute__((ext_vector_type(4))) float floatx4;

__device__ __forceinline__ void atomAddF(float* p, float v) {
    __hip_atomic_fetch_add(p, v, __ATOMIC_RELAXED, __HIP_MEMORY_SCOPE_AGENT);
}

__device__ __forceinline__ short f2bf(float v) {
    __hip_bfloat16 b = __float2bfloat16(v);
    return __builtin_bit_cast(short, b);
}

// accumulate one 256B bf16 row (held as uint4 = 8 bf16 pairs) scaled by wgt
__device__ __forceinline__ void acc8(float* acc, uint4 p, float wgt) {
    acc[0] += __uint_as_float(p.x << 16) * wgt;
    acc[1] += __uint_as_float(p.x & 0xffff0000u) * wgt;
    acc[2] += __uint_as_float(p.y << 16) * wgt;
    acc[3] += __uint_as_float(p.y & 0xffff0000u) * wgt;
    acc[4] += __uint_as_float(p.z << 16) * wgt;
    acc[5] += __uint_as_float(p.z & 0xffff0000u) * wgt;
    acc[6] += __uint_as_float(p.w << 16) * wgt;
    acc[7] += __uint_as_float(p.w & 0xffff0000u) * wgt;
}

// deg[d] = number of in-edges (dst counts)
__global__ void deg_kernel(const int* __restrict__ ei, int E, int* __restrict__ deg) {
    int e = blockIdx.x * blockDim.x + threadIdx.x;
    if (e < E) atomicAdd(&deg[ei[E + e]], 1);
}

// ---- exclusive scan of deg -> rowptr ----
__global__ void scan_partial(const int* __restrict__ deg, int N, int* __restrict__ partial) {
    __shared__ int sd[NTPB];
    int b = blockIdx.x, t = threadIdx.x;
    int base = b * CHUNK + t * 4;
    int s = 0;
#pragma unroll
    for (int k = 0; k < 4; k++) { int i = base + k; if (i < N) s += deg[i]; }
    sd[t] = s; __syncthreads();
    for (int off = NTPB / 2; off > 0; off >>= 1) {
        if (t < off) sd[t] += sd[t + off];
        __syncthreads();
    }
    if (t == 0) partial[b] = sd[0];
}

__global__ void scan_tops(const int* __restrict__ partial, int nb,
                          int* __restrict__ pscan, int* __restrict__ rowptr, int N) {
    if (threadIdx.x == 0 && blockIdx.x == 0) {
        int run = 0;
        for (int b = 0; b < nb; b++) { pscan[b] = run; run += partial[b]; }
        rowptr[N] = run;
    }
}

// also emits dinv
__global__ void scan_apply(const int* __restrict__ deg, int N, const int* __restrict__ pscan,
                           int* __restrict__ rowptr, int* __restrict__ cursor,
                           float* __restrict__ dinv) {
    __shared__ int sd[NTPB];
    int b = blockIdx.x, t = threadIdx.x;
    int base = b * CHUNK + t * 4;
    int d0 = 0, d1 = 0, d2 = 0, d3 = 0;
    if (base + 0 < N) d0 = deg[base + 0];
    if (base + 1 < N) d1 = deg[base + 1];
    if (base + 2 < N) d2 = deg[base + 2];
    if (base + 3 < N) d3 = deg[base + 3];
    int tsum = d0 + d1 + d2 + d3;
    sd[t] = tsum; __syncthreads();
    for (int s = 1; s < NTPB; s <<= 1) {
        int v = (t >= s) ? sd[t - s] : 0;
        __syncthreads();
        sd[t] += v;
        __syncthreads();
    }
    int p0 = sd[t] - tsum + pscan[b];
    int p1 = p0 + d0, p2 = p1 + d1, p3 = p2 + d2;
    if (base + 0 < N) { rowptr[base + 0] = p0; cursor[base + 0] = p0; dinv[base + 0] = rsqrtf((float)(d0 + 1)); }
    if (base + 1 < N) { rowptr[base + 1] = p1; cursor[base + 1] = p1; dinv[base + 1] = rsqrtf((float)(d1 + 1)); }
    if (base + 2 < N) { rowptr[base + 2] = p2; cursor[base + 2] = p2; dinv[base + 2] = rsqrtf((float)(d2 + 1)); }
    if (base + 3 < N) { rowptr[base + 3] = p3; cursor[base + 3] = p3; dinv[base + 3] = rsqrtf((float)(d3 + 1)); }
}

// bucket-scatter: dst-grouped {src, w} (8 B/edge)
__global__ void scatter_kernel(const int* __restrict__ ei, int E, const float* __restrict__ dinv,
                               int* __restrict__ cursor, int2* __restrict__ csr) {
    int e = blockIdx.x * blockDim.x + threadIdx.x;
    if (e >= E) return;
    int s = ei[e], d = ei[E + e];
    int pos = atomicAdd(&cursor[d], 1);
    float w = dinv[s] * dinv[d];
    csr[pos] = make_int2(s, __float_as_int(w));
}

// layer-1 CSR gather on raw x (3-wide), 4-edge unroll (independent addresses)
__global__ void l1_gather(const float* __restrict__ x, const float* __restrict__ dinv,
                          const int* __restrict__ rowptr, const int2* __restrict__ csr,
                          float* __restrict__ aggx, int N) {
    int n = blockIdx.x * blockDim.x + threadIdx.x;
    if (n >= N) return;
    float di = dinv[n], d2 = di * di;
    float a0 = x[3 * n + 0] * d2, a1 = x[3 * n + 1] * d2, a2 = x[3 * n + 2] * d2;
    int beg = rowptr[n], end = rowptr[n + 1];
    int i = beg;
    for (; i + 4 <= end; i += 4) {
        int2 c0 = csr[i], c1 = csr[i + 1], c2 = csr[i + 2], c3 = csr[i + 3];
        float w0 = __int_as_float(c0.y), w1 = __int_as_float(c1.y);
        float w2 = __int_as_float(c2.y), w3 = __int_as_float(c3.y);
        float x00 = x[3 * c0.x], x01 = x[3 * c0.x + 1], x02 = x[3 * c0.x + 2];
        float x10 = x[3 * c1.x], x11 = x[3 * c1.x + 1], x12 = x[3 * c1.x + 2];
        float x20 = x[3 * c2.x], x21 = x[3 * c2.x + 1], x22 = x[3 * c2.x + 2];
        float x30 = x[3 * c3.x], x31 = x[3 * c3.x + 1], x32 = x[3 * c3.x + 2];
        a0 += x00 * w0 + x10 * w1 + x20 * w2 + x30 * w3;
        a1 += x01 * w0 + x11 * w1 + x21 * w2 + x31 * w3;
        a2 += x02 * w0 + x12 * w1 + x22 * w2 + x32 * w3;
    }
    for (; i < end; ++i) {
        int2 c = csr[i];
        float w = __int_as_float(c.y);
        a0 += x[3 * c.x + 0] * w;
        a1 += x[3 * c.x + 1] * w;
        a2 += x[3 * c.x + 2] * w;
    }
    aggx[3 * n + 0] = a0; aggx[3 * n + 1] = a1; aggx[3 * n + 2] = a2;
}

// pre-pack W2 into bf16 B-fragments for mfma_f32_16x16x32_bf16:
// Bp[((nt*4+c)*64 + lane)*8 + jj] = bf16(W2[(c*32 + (lane>>4)*8 + jj)*128 + nt*16 + (lane&15)])
__global__ void bpack_kernel(const float* __restrict__ W2, __hip_bfloat16* __restrict__ Bp) {
    int idx = blockIdx.x * blockDim.x + threadIdx.x;  // 0..2047
    if (idx >= 2048) return;
    int frag = idx >> 6, lane = idx & 63;
    int nt = frag >> 2, c = frag & 3, quad = lane >> 4, m16 = lane & 15;
#pragma unroll
    for (int jj = 0; jj < 8; jj++) {
        int k = c * 32 + quad * 8 + jj;
        Bp[idx * 8 + jj] = __float2bfloat16(W2[k * H + nt * 16 + m16]);
    }
}

// MFMA gemm: one wave per 16-row tile. A = relu(aggx@W1+b1) built in regs (bf16),
// B = pre-packed W2 frags, D -> bf16 hB.
// A layout: A[m=lane&15][k=quad*8+jj]; C/D layout: col=lane&15, row=quad*4+reg.
__global__ void gemm2_mfma(const float* __restrict__ aggx, const float* __restrict__ W1,
                           const float* __restrict__ b1, const __hip_bfloat16* __restrict__ Bp,
                           __hip_bfloat16* __restrict__ hBb, int N) {
    int wave = threadIdx.x >> 6, lane = threadIdx.x & 63;
    int quad = lane >> 4, m16 = lane & 15;
    int tile = blockIdx.x * 4 + wave;
    int rowbase = tile * 16;
    if (rowbase >= N) return;
    int m = rowbase + m16;
    float a0 = 0.f, a1 = 0.f, a2 = 0.f;
    if (m < N) { a0 = aggx[3 * m]; a1 = aggx[3 * m + 1]; a2 = aggx[3 * m + 2]; }
    short8 af[4];
#pragma unroll
    for (int c = 0; c < 4; c++) {
#pragma unroll
        for (int jj = 0; jj < 8; jj++) {
            int k = c * 32 + quad * 8 + jj;
            float h = fmaxf(a0 * W1[k] + a1 * W1[H + k] + a2 * W1[2 * H + k] + b1[k], 0.f);
            af[c][jj] = f2bf(h);
        }
    }
    const short8* bp = (const short8*)Bp;
    floatx4 acc[8];
#pragma unroll
    for (int nt = 0; nt < 8; nt++) acc[nt] = (floatx4){0.f, 0.f, 0.f, 0.f};
#pragma unroll
    for (int nt = 0; nt < 8; nt++) {
#pragma unroll
        for (int c = 0; c < 4; c++) {
            short8 bf = bp[(nt * 4 + c) * 64 + lane];
            acc[nt] = __builtin_amdgcn_mfma_f32_16x16x32_bf16(af[c], bf, acc[nt], 0, 0, 0);
        }
    }
#pragma unroll
    for (int nt = 0; nt < 8; nt++) {
#pragma unroll
        for (int reg = 0; reg < 4; reg++) {
            int row = rowbase + quad * 4 + reg;
            int col = nt * 16 + m16;
            if (row < N) hBb[(size_t)row * H + col] = __float2bfloat16(acc[nt][reg]);
        }
    }
}

// layer-2 gather: wave per dst node, 4 lane-groups x 16 lanes; each group reads one
// 256B bf16 row as uint4 (16B/lane) -> 4 edges per wave-instruction, 16 edges in flight.
__global__ void gather_pool(const uint4* __restrict__ hB4, const float* __restrict__ dinv,
                            const int* __restrict__ rowptr, const int2* __restrict__ csr,
                            const float* __restrict__ b2, const float* __restrict__ Wc,
                            const int* __restrict__ batch,
                            float* __restrict__ gsum, int* __restrict__ gcnt, int N) {
    __shared__ float sb2[H];
    __shared__ float swc[H];
    __shared__ int2 sls[GP_WPB][64];
    int t = threadIdx.x;
    if (t < H) { sb2[t] = b2[t]; swc[t] = Wc[t]; }
    __syncthreads();
    int wv = t >> 6, lane = t & 63;
    int node = blockIdx.x * GP_WPB + wv;
    if (node >= N) return;
    int g = lane >> 4;    // edge group 0..3
    int l16 = lane & 15;  // 16B slot within row -> dims [8*l16, 8*l16+8)
    float acc[8];
#pragma unroll
    for (int j = 0; j < 8; j++) acc[j] = 0.f;
    int beg = rowptr[node], end = rowptr[node + 1];
    for (int base = beg; base < end; base += 64) {
        int m = end - base; if (m > 64) m = 64;
        int2 c = (lane < m) ? csr[base + lane] : make_int2(0, 0);
        sls[wv][lane] = c;  // same-wave produce/consume: lgkmcnt only, no barrier
        int mp = (m + 15) & ~15;  // pads are {src=0,w=0}: harmless row-0 loads
        for (int k = 0; k < mp; k += 16) {
            int2 cA = sls[wv][k + g];
            int2 cB = sls[wv][k + 4 + g];
            int2 cC = sls[wv][k + 8 + g];
            int2 cD = sls[wv][k + 12 + g];
            uint4 pA = hB4[(size_t)cA.x * 16 + l16];
            uint4 pB = hB4[(size_t)cB.x * 16 + l16];
            uint4 pC = hB4[(size_t)cC.x * 16 + l16];
            uint4 pD = hB4[(size_t)cD.x * 16 + l16];
            acc8(acc, pA, __int_as_float(cA.y));
            acc8(acc, pB, __int_as_float(cB.y));
            acc8(acc, pC, __int_as_float(cC.y));
            acc8(acc, pD, __int_as_float(cD.y));
        }
    }
    // combine the 4 edge groups (butterfly leaves every lane with the group-sum)
#pragma unroll
    for (int j = 0; j < 8; j++) {
        acc[j] += __shfl_xor(acc[j], 16);
        acc[j] += __shfl_xor(acc[j], 32);
    }
    // self-loop
    float di = dinv[node], d2 = di * di;
    uint4 ps = hB4[(size_t)node * 16 + l16];
    acc8(acc, ps, d2);
    // bias + relu + Wc dot over this lane's 8 dims
    float dot = 0.f;
#pragma unroll
    for (int j = 0; j < 8; j++) {
        float v = fmaxf(acc[j] + sb2[8 * l16 + j], 0.f);
        dot += v * swc[8 * l16 + j];
    }
    // reduce across the 16 slots (groups hold identical copies)
    dot += __shfl_xor(dot, 1);
    dot += __shfl_xor(dot, 2);
    dot += __shfl_xor(dot, 4);
    dot += __shfl_xor(dot, 8);
    if (lane == 0) {
        int gidx = batch[node];
        atomAddF(&gsum[gidx], dot);
        atomicAdd(&gcnt[gidx], 1);
    }
}

__global__ void out_kernel(const float* __restrict__ gsum, const int* __restrict__ gcnt,
                           const float* __restrict__ bc, float* __restrict__ out, int G) {
    int g = blockIdx.x * blockDim.x + threadIdx.x;
    if (g >= G) return;
    float c = fmaxf((float)gcnt[g], 1.f);
    float logit = gsum[g] / c + bc[0];
    out[g] = 1.f / (1.f + expf(-logit));
}

extern "C" void kernel_launch(void* const* d_in, const int* in_sizes, int n_in,
                              void* d_out, int out_size, void* d_ws, size_t ws_size,
                              hipStream_t stream) {
    const float* x     = (const float*)d_in[0];
    const int*   ei    = (const int*)d_in[1];
    const int*   batch = (const int*)d_in[2];
    const float* W1    = (const float*)d_in[3];
    const float* b1    = (const float*)d_in[4];
    const float* W2    = (const float*)d_in[5];
    const float* b2    = (const float*)d_in[6];
    const float* Wc    = (const float*)d_in[7];
    const float* bc    = (const float*)d_in[8];
    float* out = (float*)d_out;

    int N = in_sizes[2];
    int E = in_sizes[1] / 2;
    int G = out_size;
    int NB = (N + CHUNK - 1) / CHUNK;

    char* ws = (char*)d_ws;
    size_t off = 0;
    auto alloc = [&](size_t bytes) {
        void* p = ws + off;
        off += (bytes + 255) & ~(size_t)255;
        return p;
    };
    __hip_bfloat16* hBb = (__hip_bfloat16*)alloc((size_t)N * H * sizeof(__hip_bfloat16));
    float* aggx   = (float*)alloc((size_t)N * 3 * sizeof(float));
    // deg/gsum/gcnt contiguous -> single memset
    int*   deg    = (int*)  alloc((size_t)N * sizeof(int));
    float* gsum   = (float*)alloc((size_t)G * sizeof(float));
    int*   gcnt   = (int*)  alloc((size_t)G * sizeof(int));
    char*  zero_end = ws + off;
    int*   rowptr = (int*)  alloc((size_t)(N + 1) * sizeof(int));
    int*   cursor = (int*)  alloc((size_t)N * sizeof(int));
    float* dinv   = (float*)alloc((size_t)N * sizeof(float));
    int2*  csr    = (int2*) alloc((size_t)E * sizeof(int2));
    __hip_bfloat16* Bp = (__hip_bfloat16*)alloc((size_t)H * H * sizeof(__hip_bfloat16));
    int*   partial= (int*)  alloc((size_t)NB * sizeof(int));
    int*   pscan  = (int*)  alloc((size_t)NB * sizeof(int));

    (void)hipMemsetAsync(deg, 0, (size_t)(zero_end - (char*)deg), stream);

    deg_kernel<<<(E + NTPB - 1) / NTPB, NTPB, 0, stream>>>(ei, E, deg);

    scan_partial<<<NB, NTPB, 0, stream>>>(deg, N, partial);
    scan_tops<<<1, 64, 0, stream>>>(partial, NB, pscan, rowptr, N);
    scan_apply<<<NB, NTPB, 0, stream>>>(deg, N, pscan, rowptr, cursor, dinv);

    scatter_kernel<<<(E + NTPB - 1) / NTPB, NTPB, 0, stream>>>(ei, E, dinv, cursor, csr);

    bpack_kernel<<<8, NTPB, 0, stream>>>(W2, Bp);

    l1_gather<<<(N + NTPB - 1) / NTPB, NTPB, 0, stream>>>(x, dinv, rowptr, csr, aggx, N);

    {
        int ntiles = (N + 15) / 16;
        gemm2_mfma<<<(ntiles + 3) / 4, NTPB, 0, stream>>>(aggx, W1, b1, Bp, hBb, N);
    }

    gather_pool<<<(N + GP_WPB - 1) / GP_WPB, NTPB, 0, stream>>>(
        (const uint4*)hBb, dinv, rowptr, csr, b2, Wc, batch, gsum, gcnt, N);

    out_kernel<<<(G + NTPB - 1) / NTPB, NTPB, 0, stream>>>(gsum, gcnt, bc, out, G);
}

// Round 7
// 480.511 us; speedup vs baseline: 7.1120x; 1.1051x over previous
//
#include <hip/hip_runtime.h>
#include <hip/hip_bf16.h>
#include <math.h>

#define H 128
#define NTPB 256
#define CHUNK 1024  // elements per scan block (256 threads x 4)
#define SRC_MASK 0x1FFFFu
#define WSCALE (1.0f / 32767.0f)

typedef __attribute__((ext_vector_type(8))) short short8;
typedef __attribute__((ext_vector_type(4))) float floatx4;

__device__ __forceinline__ void atomAddF(float* p, float v) {
    __hip_atomic_fetch_add(p, v, __ATOMIC_RELAXED, __HIP_MEMORY_SCOPE_AGENT);
}

__device__ __forceinline__ short f2bf(float v) {
    __hip_bfloat16 b = __float2bfloat16(v);
    return __builtin_bit_cast(short, b);
}

// accumulate one 256B bf16 row chunk (uint4 = 8 bf16) scaled by wgt
__device__ __forceinline__ void acc8(float* acc, uint4 p, float wgt) {
    acc[0] += __uint_as_float(p.x << 16) * wgt;
    acc[1] += __uint_as_float(p.x & 0xffff0000u) * wgt;
    acc[2] += __uint_as_float(p.y << 16) * wgt;
    acc[3] += __uint_as_float(p.y & 0xffff0000u) * wgt;
    acc[4] += __uint_as_float(p.z << 16) * wgt;
    acc[5] += __uint_as_float(p.z & 0xffff0000u) * wgt;
    acc[6] += __uint_as_float(p.w << 16) * wgt;
    acc[7] += __uint_as_float(p.w & 0xffff0000u) * wgt;
}

// deg[d] = number of in-edges (dst counts)
__global__ void deg_kernel(const int* __restrict__ ei, int E, int* __restrict__ deg) {
    int e = blockIdx.x * blockDim.x + threadIdx.x;
    if (e < E) atomicAdd(&deg[ei[E + e]], 1);
}

// ---- exclusive scan of deg -> rowptr ----
__global__ void scan_partial(const int* __restrict__ deg, int N, int* __restrict__ partial) {
    __shared__ int sd[NTPB];
    int b = blockIdx.x, t = threadIdx.x;
    int base = b * CHUNK + t * 4;
    int s = 0;
#pragma unroll
    for (int k = 0; k < 4; k++) { int i = base + k; if (i < N) s += deg[i]; }
    sd[t] = s; __syncthreads();
    for (int off = NTPB / 2; off > 0; off >>= 1) {
        if (t < off) sd[t] += sd[t + off];
        __syncthreads();
    }
    if (t == 0) partial[b] = sd[0];
}

__global__ void scan_tops(const int* __restrict__ partial, int nb,
                          int* __restrict__ pscan, int* __restrict__ rowptr, int N) {
    if (threadIdx.x == 0 && blockIdx.x == 0) {
        int run = 0;
        for (int b = 0; b < nb; b++) { pscan[b] = run; run += partial[b]; }
        rowptr[N] = run;
    }
}

// also emits dinv
__global__ void scan_apply(const int* __restrict__ deg, int N, const int* __restrict__ pscan,
                           int* __restrict__ rowptr, int* __restrict__ cursor,
                           float* __restrict__ dinv) {
    __shared__ int sd[NTPB];
    int b = blockIdx.x, t = threadIdx.x;
    int base = b * CHUNK + t * 4;
    int d0 = 0, d1 = 0, d2 = 0, d3 = 0;
    if (base + 0 < N) d0 = deg[base + 0];
    if (base + 1 < N) d1 = deg[base + 1];
    if (base + 2 < N) d2 = deg[base + 2];
    if (base + 3 < N) d3 = deg[base + 3];
    int tsum = d0 + d1 + d2 + d3;
    sd[t] = tsum; __syncthreads();
    for (int s = 1; s < NTPB; s <<= 1) {
        int v = (t >= s) ? sd[t - s] : 0;
        __syncthreads();
        sd[t] += v;
        __syncthreads();
    }
    int p0 = sd[t] - tsum + pscan[b];
    int p1 = p0 + d0, p2 = p1 + d1, p3 = p2 + d2;
    if (base + 0 < N) { rowptr[base + 0] = p0; cursor[base + 0] = p0; dinv[base + 0] = rsqrtf((float)(d0 + 1)); }
    if (base + 1 < N) { rowptr[base + 1] = p1; cursor[base + 1] = p1; dinv[base + 1] = rsqrtf((float)(d1 + 1)); }
    if (base + 2 < N) { rowptr[base + 2] = p2; cursor[base + 2] = p2; dinv[base + 2] = rsqrtf((float)(d2 + 1)); }
    if (base + 3 < N) { rowptr[base + 3] = p3; cursor[base + 3] = p3; dinv[base + 3] = rsqrtf((float)(d3 + 1)); }
}

// bucket-scatter: dst-grouped packed edge = (w*32767)<<17 | src  (4 B/edge)
__global__ void scatter_kernel(const int* __restrict__ ei, int E, const float* __restrict__ dinv,
                               int* __restrict__ cursor, unsigned* __restrict__ csr) {
    int e = blockIdx.x * blockDim.x + threadIdx.x;
    if (e >= E) return;
    int s = ei[e], d = ei[E + e];
    int pos = atomicAdd(&cursor[d], 1);
    float w = dinv[s] * dinv[d];
    unsigned wq = (unsigned)(w * 32767.0f + 0.5f);
    csr[pos] = (wq << 17) | (unsigned)s;
}

// layer-1 CSR gather on raw x (3-wide), 4-edge unroll, packed csr
__global__ void l1_gather(const float* __restrict__ x, const float* __restrict__ dinv,
                          const int* __restrict__ rowptr, const unsigned* __restrict__ csr,
                          float* __restrict__ aggx, int N) {
    int n = blockIdx.x * blockDim.x + threadIdx.x;
    if (n >= N) return;
    float di = dinv[n], d2 = di * di;
    float a0 = x[3 * n + 0] * d2, a1 = x[3 * n + 1] * d2, a2 = x[3 * n + 2] * d2;
    int beg = rowptr[n], end = rowptr[n + 1];
    int i = beg;
    for (; i + 4 <= end; i += 4) {
        unsigned c0 = csr[i], c1 = csr[i + 1], c2 = csr[i + 2], c3 = csr[i + 3];
        int s0 = c0 & SRC_MASK, s1 = c1 & SRC_MASK, s2 = c2 & SRC_MASK, s3 = c3 & SRC_MASK;
        float w0 = (float)(c0 >> 17) * WSCALE, w1 = (float)(c1 >> 17) * WSCALE;
        float w2 = (float)(c2 >> 17) * WSCALE, w3 = (float)(c3 >> 17) * WSCALE;
        float x00 = x[3 * s0], x01 = x[3 * s0 + 1], x02 = x[3 * s0 + 2];
        float x10 = x[3 * s1], x11 = x[3 * s1 + 1], x12 = x[3 * s1 + 2];
        float x20 = x[3 * s2], x21 = x[3 * s2 + 1], x22 = x[3 * s2 + 2];
        float x30 = x[3 * s3], x31 = x[3 * s3 + 1], x32 = x[3 * s3 + 2];
        a0 += x00 * w0 + x10 * w1 + x20 * w2 + x30 * w3;
        a1 += x01 * w0 + x11 * w1 + x21 * w2 + x31 * w3;
        a2 += x02 * w0 + x12 * w1 + x22 * w2 + x32 * w3;
    }
    for (; i < end; ++i) {
        unsigned c = csr[i];
        int s = c & SRC_MASK;
        float w = (float)(c >> 17) * WSCALE;
        a0 += x[3 * s + 0] * w;
        a1 += x[3 * s + 1] * w;
        a2 += x[3 * s + 2] * w;
    }
    aggx[3 * n + 0] = a0; aggx[3 * n + 1] = a1; aggx[3 * n + 2] = a2;
}

// pre-pack W2 into bf16 B-fragments for mfma_f32_16x16x32_bf16
__global__ void bpack_kernel(const float* __restrict__ W2, __hip_bfloat16* __restrict__ Bp) {
    int idx = blockIdx.x * blockDim.x + threadIdx.x;  // 0..2047
    if (idx >= 2048) return;
    int frag = idx >> 6, lane = idx & 63;
    int nt = frag >> 2, c = frag & 3, quad = lane >> 4, m16 = lane & 15;
#pragma unroll
    for (int jj = 0; jj < 8; jj++) {
        int k = c * 32 + quad * 8 + jj;
        Bp[idx * 8 + jj] = __float2bfloat16(W2[k * H + nt * 16 + m16]);
    }
}

// MFMA gemm: one wave per 16-row tile. A = relu(aggx@W1+b1) built in regs (bf16),
// B = pre-packed W2 frags, D -> bf16 hB.
__global__ void gemm2_mfma(const float* __restrict__ aggx, const float* __restrict__ W1,
                           const float* __restrict__ b1, const __hip_bfloat16* __restrict__ Bp,
                           __hip_bfloat16* __restrict__ hBb, int N) {
    int wave = threadIdx.x >> 6, lane = threadIdx.x & 63;
    int quad = lane >> 4, m16 = lane & 15;
    int tile = blockIdx.x * 4 + wave;
    int rowbase = tile * 16;
    if (rowbase >= N) return;
    int m = rowbase + m16;
    float a0 = 0.f, a1 = 0.f, a2 = 0.f;
    if (m < N) { a0 = aggx[3 * m]; a1 = aggx[3 * m + 1]; a2 = aggx[3 * m + 2]; }
    short8 af[4];
#pragma unroll
    for (int c = 0; c < 4; c++) {
#pragma unroll
        for (int jj = 0; jj < 8; jj++) {
            int k = c * 32 + quad * 8 + jj;
            float h = fmaxf(a0 * W1[k] + a1 * W1[H + k] + a2 * W1[2 * H + k] + b1[k], 0.f);
            af[c][jj] = f2bf(h);
        }
    }
    const short8* bp = (const short8*)Bp;
    floatx4 acc[8];
#pragma unroll
    for (int nt = 0; nt < 8; nt++) acc[nt] = (floatx4){0.f, 0.f, 0.f, 0.f};
#pragma unroll
    for (int nt = 0; nt < 8; nt++) {
#pragma unroll
        for (int c = 0; c < 4; c++) {
            short8 bf = bp[(nt * 4 + c) * 64 + lane];
            acc[nt] = __builtin_amdgcn_mfma_f32_16x16x32_bf16(af[c], bf, acc[nt], 0, 0, 0);
        }
    }
#pragma unroll
    for (int nt = 0; nt < 8; nt++) {
#pragma unroll
        for (int reg = 0; reg < 4; reg++) {
            int row = rowbase + quad * 4 + reg;
            int col = nt * 16 + m16;
            if (row < N) hBb[(size_t)row * H + col] = __float2bfloat16(acc[nt][reg]);
        }
    }
}

// layer-2 gather: one 16-lane group per NODE (4 nodes/wave, 16/block).
// Row read = 16 lanes x uint4 (256 B). 4 edges unrolled per iteration; the wave
// interleaves 4 independent nodes' streams. No LDS staging, per-node epilogue
// runs 4-way parallel, reduction is 4 shuffles within the group.
__global__ void gather_pool(const uint4* __restrict__ hB4, const float* __restrict__ dinv,
                            const int* __restrict__ rowptr, const unsigned* __restrict__ csr,
                            const float* __restrict__ b2, const float* __restrict__ Wc,
                            const int* __restrict__ batch,
                            float* __restrict__ gsum, int* __restrict__ gcnt, int N) {
    __shared__ float sb2[H];
    __shared__ float swc[H];
    int t = threadIdx.x;
    if (t < H) { sb2[t] = b2[t]; swc[t] = Wc[t]; }
    __syncthreads();
    int grp = t >> 4;       // group 0..15 within block
    int l16 = t & 15;       // lane within group -> dims [8*l16, 8*l16+8)
    int node = blockIdx.x * 16 + grp;
    if (node >= N) return;
    float acc[8];
#pragma unroll
    for (int j = 0; j < 8; j++) acc[j] = 0.f;
    int beg = rowptr[node], end = rowptr[node + 1];
    for (int i = beg; i < end; i += 4) {
        int rem = end - i;
        unsigned c0 = csr[i];
        unsigned c1 = (rem > 1) ? csr[i + 1] : 0u;
        unsigned c2 = (rem > 2) ? csr[i + 2] : 0u;
        unsigned c3 = (rem > 3) ? csr[i + 3] : 0u;   // pad {src=0,w=0}: L1-hot row-0 load
        uint4 p0 = hB4[(size_t)(c0 & SRC_MASK) * 16 + l16];
        uint4 p1 = hB4[(size_t)(c1 & SRC_MASK) * 16 + l16];
        uint4 p2 = hB4[(size_t)(c2 & SRC_MASK) * 16 + l16];
        uint4 p3 = hB4[(size_t)(c3 & SRC_MASK) * 16 + l16];
        acc8(acc, p0, (float)(c0 >> 17) * WSCALE);
        acc8(acc, p1, (float)(c1 >> 17) * WSCALE);
        acc8(acc, p2, (float)(c2 >> 17) * WSCALE);
        acc8(acc, p3, (float)(c3 >> 17) * WSCALE);
    }
    // self-loop
    float di = dinv[node];
    uint4 ps = hB4[(size_t)node * 16 + l16];
    acc8(acc, ps, di * di);
    // bias + relu + Wc dot over this lane's 8 dims
    float dot = 0.f;
#pragma unroll
    for (int j = 0; j < 8; j++) {
        float v = fmaxf(acc[j] + sb2[8 * l16 + j], 0.f);
        dot += v * swc[8 * l16 + j];
    }
    // reduce across the 16 lanes of the group (xor<16 stays in-group)
    dot += __shfl_xor(dot, 1);
    dot += __shfl_xor(dot, 2);
    dot += __shfl_xor(dot, 4);
    dot += __shfl_xor(dot, 8);
    if (l16 == 0) {
        int gidx = batch[node];
        atomAddF(&gsum[gidx], dot);
        atomicAdd(&gcnt[gidx], 1);
    }
}

__global__ void out_kernel(const float* __restrict__ gsum, const int* __restrict__ gcnt,
                           const float* __restrict__ bc, float* __restrict__ out, int G) {
    int g = blockIdx.x * blockDim.x + threadIdx.x;
    if (g >= G) return;
    float c = fmaxf((float)gcnt[g], 1.f);
    float logit = gsum[g] / c + bc[0];
    out[g] = 1.f / (1.f + expf(-logit));
}

extern "C" void kernel_launch(void* const* d_in, const int* in_sizes, int n_in,
                              void* d_out, int out_size, void* d_ws, size_t ws_size,
                              hipStream_t stream) {
    const float* x     = (const float*)d_in[0];
    const int*   ei    = (const int*)d_in[1];
    const int*   batch = (const int*)d_in[2];
    const float* W1    = (const float*)d_in[3];
    const float* b1    = (const float*)d_in[4];
    const float* W2    = (const float*)d_in[5];
    const float* b2    = (const float*)d_in[6];
    const float* Wc    = (const float*)d_in[7];
    const float* bc    = (const float*)d_in[8];
    float* out = (float*)d_out;

    int N = in_sizes[2];
    int E = in_sizes[1] / 2;
    int G = out_size;
    int NB = (N + CHUNK - 1) / CHUNK;

    char* ws = (char*)d_ws;
    size_t off = 0;
    auto alloc = [&](size_t bytes) {
        void* p = ws + off;
        off += (bytes + 255) & ~(size_t)255;
        return p;
    };
    __hip_bfloat16* hBb = (__hip_bfloat16*)alloc((size_t)N * H * sizeof(__hip_bfloat16));
    float* aggx   = (float*)alloc((size_t)N * 3 * sizeof(float));
    // deg/gsum/gcnt contiguous -> single memset
    int*   deg    = (int*)  alloc((size_t)N * sizeof(int));
    float* gsum   = (float*)alloc((size_t)G * sizeof(float));
    int*   gcnt   = (int*)  alloc((size_t)G * sizeof(int));
    char*  zero_end = ws + off;
    int*   rowptr = (int*)  alloc((size_t)(N + 1) * sizeof(int));
    int*   cursor = (int*)  alloc((size_t)N * sizeof(int));
    float* dinv   = (float*)alloc((size_t)N * sizeof(float));
    unsigned* csr = (unsigned*)alloc((size_t)E * sizeof(unsigned));
    __hip_bfloat16* Bp = (__hip_bfloat16*)alloc((size_t)H * H * sizeof(__hip_bfloat16));
    int*   partial= (int*)  alloc((size_t)NB * sizeof(int));
    int*   pscan  = (int*)  alloc((size_t)NB * sizeof(int));

    (void)hipMemsetAsync(deg, 0, (size_t)(zero_end - (char*)deg), stream);

    deg_kernel<<<(E + NTPB - 1) / NTPB, NTPB, 0, stream>>>(ei, E, deg);

    scan_partial<<<NB, NTPB, 0, stream>>>(deg, N, partial);
    scan_tops<<<1, 64, 0, stream>>>(partial, NB, pscan, rowptr, N);
    scan_apply<<<NB, NTPB, 0, stream>>>(deg, N, pscan, rowptr, cursor, dinv);

    scatter_kernel<<<(E + NTPB - 1) / NTPB, NTPB, 0, stream>>>(ei, E, dinv, cursor, csr);

    bpack_kernel<<<8, NTPB, 0, stream>>>(W2, Bp);

    l1_gather<<<(N + NTPB - 1) / NTPB, NTPB, 0, stream>>>(x, dinv, rowptr, csr, aggx, N);

    {
        int ntiles = (N + 15) / 16;
        gemm2_mfma<<<(ntiles + 3) / 4, NTPB, 0, stream>>>(aggx, W1, b1, Bp, hBb, N);
    }

    gather_pool<<<(N + 15) / 16, NTPB, 0, stream>>>(
        (const uint4*)hBb, dinv, rowptr, csr, b2, Wc, batch, gsum, gcnt, N);

    out_kernel<<<(G + NTPB - 1) / NTPB, NTPB, 0, stream>>>(gsum, gcnt, bc, out, G);
}